// Round 1
// baseline (406.144 us; speedup 1.0000x reference)
//
#include <hip/hip_runtime.h>

#define B_ 8
#define T_ 4096
#define D_ 1024
#define H_ 8
#define HD_ 128
#define P_ 1024
#define OUT_ 1024
#define W_ 128
#define NC_ 64
#define CHUNK_ 64   // T_/NC_

// K1: qp[h*D+d] = (1/sqrt(HD)) * sum_e w_kv[d*2P + h*HD + e] * query[h*HD+e]
__global__ void k_qproj(const float* __restrict__ w_kv, const float* __restrict__ query,
                        float* __restrict__ qp) {
  int idx = blockIdx.x * blockDim.x + threadIdx.x;  // 8192 = H*D
  int h = idx >> 10, d = idx & 1023;
  const float* col = w_kv + (size_t)d * (2 * P_) + h * HD_;
  const float* q = query + h * HD_;
  float a = 0.f;
#pragma unroll 8
  for (int e = 0; e < HD_; ++e) a += col[e] * q[e];
  qp[idx] = a * 0.08838834764831845f;  // 1/sqrt(128)
}

// K2: logits[(b*H+h)*T + t] = dot(x[b,t,:], qp[h,:])   (wave per row-pair)
__global__ void __launch_bounds__(256) k_logits(const float* __restrict__ x,
                                                const float* __restrict__ qp,
                                                float* __restrict__ logits) {
  __shared__ float s_qp[H_ * D_];
  for (int i = threadIdx.x; i < H_ * D_ / 4; i += 256)
    ((float4*)s_qp)[i] = ((const float4*)qp)[i];
  __syncthreads();
  int wid = threadIdx.x >> 6, lane = threadIdx.x & 63;
  int nw = gridDim.x * 4;
  for (int pr = blockIdx.x * 4 + wid; pr < B_ * T_ / 2; pr += nw) {
    int row0 = pr * 2;
    const float4* xr0 = (const float4*)(x + (size_t)row0 * D_);
    const float4* xr1 = (const float4*)(x + (size_t)(row0 + 1) * D_);
    float4 xv0[4], xv1[4];
#pragma unroll
    for (int j = 0; j < 4; ++j) { xv0[j] = xr0[lane + 64 * j]; xv1[j] = xr1[lane + 64 * j]; }
    float acc0[H_], acc1[H_];
#pragma unroll
    for (int h = 0; h < H_; ++h) {
      const float4* qh = (const float4*)(s_qp + h * D_);
      float a0 = 0.f, a1 = 0.f;
#pragma unroll
      for (int j = 0; j < 4; ++j) {
        float4 q = qh[lane + 64 * j];
        a0 += xv0[j].x * q.x + xv0[j].y * q.y + xv0[j].z * q.z + xv0[j].w * q.w;
        a1 += xv1[j].x * q.x + xv1[j].y * q.y + xv1[j].z * q.z + xv1[j].w * q.w;
      }
      acc0[h] = a0; acc1[h] = a1;
    }
#pragma unroll
    for (int h = 0; h < H_; ++h) {
      float a0 = acc0[h], a1 = acc1[h];
#pragma unroll
      for (int off = 32; off; off >>= 1) {
        a0 += __shfl_down(a0, off, 64);
        a1 += __shfl_down(a1, off, 64);
      }
      if (lane == 0) {
        int b = row0 >> 12, t = row0 & (T_ - 1);
        logits[((b * H_ + h) << 12) + t] = a0;
        logits[((b * H_ + h) << 12) + t + 1] = a1;
      }
    }
  }
}

// K3: per-window softmax stats + per-token accumulated weights (incl. 1/W factor)
__global__ void __launch_bounds__(128) k_weights(const float* __restrict__ logits,
                                                 float* __restrict__ weight) {
  int bh = blockIdx.x;  // 64 = B*H
  const float* L = logits + (size_t)bh * T_;
  __shared__ float sl[T_];
  __shared__ float sm[W_], srs[W_];
  for (int i = threadIdx.x; i < T_ / 4; i += 128)
    ((float4*)sl)[i] = ((const float4*)L)[i];
  __syncthreads();
  {
    int w = threadIdx.x;  // one window per thread, 128 windows
    int start = w * 32;
    int cnt = min(64, T_ - start);  // window 127 has only 32 valid entries
    float m = -1e30f;
    for (int i = 0; i < cnt; ++i) m = fmaxf(m, sl[start + i]);
    float s = 0.f;
    for (int i = 0; i < cnt; ++i) s += __expf(sl[start + i] - m);
    sm[w] = m;
    srs[w] = 1.0f / s;
  }
  __syncthreads();
  const float invW = 1.0f / (float)W_;
  for (int t = threadIdx.x; t < T_; t += 128) {
    float l = sl[t];
    int w1 = t >> 5;  // every token is in windows w1 and w1-1 (when w1>0)
    float acc = __expf(l - sm[w1]) * srs[w1];
    if (w1 > 0) acc += __expf(l - sm[w1 - 1]) * srs[w1 - 1];
    weight[(size_t)bh * T_ + t] = acc * invW;
  }
}

// K4: partial[c][b][h][d] = sum_{t in chunk c} weight[b,h,t] * x[b,t,d]
__global__ void __launch_bounds__(256) k_yacc(const float* __restrict__ x,
                                              const float* __restrict__ weight,
                                              float* __restrict__ partial) {
  int b = blockIdx.x >> 6;  // NC_=64
  int c = blockIdx.x & 63;
  int t0 = c * CHUNK_;
  __shared__ float sw[H_][CHUNK_];
  for (int i = threadIdx.x; i < H_ * CHUNK_; i += 256) {
    int h = i / CHUNK_, tt = i % CHUNK_;
    sw[h][tt] = weight[((b * H_ + h) << 12) + t0 + tt];
  }
  __syncthreads();
  float4 acc[H_];
#pragma unroll
  for (int h = 0; h < H_; ++h) acc[h] = make_float4(0.f, 0.f, 0.f, 0.f);
  const float4* xb = (const float4*)(x + ((size_t)b * T_ + t0) * D_);
  for (int tt = 0; tt < CHUNK_; ++tt) {
    float4 xv = xb[tt * (D_ / 4) + threadIdx.x];
#pragma unroll
    for (int h = 0; h < H_; ++h) {
      float wv = sw[h][tt];
      acc[h].x += wv * xv.x; acc[h].y += wv * xv.y;
      acc[h].z += wv * xv.z; acc[h].w += wv * xv.w;
    }
  }
  float4* pp = (float4*)(partial + (((size_t)(c * B_ + b) * H_) << 10));
#pragma unroll
  for (int h = 0; h < H_; ++h) pp[h * (D_ / 4) + threadIdx.x] = acc[h];
}

// K5: y[b*H+h][d] = sum_c partial[c][b][h][d]
__global__ void __launch_bounds__(256) k_reduce_y(const float* __restrict__ partial,
                                                  float* __restrict__ y) {
  int i = blockIdx.x * blockDim.x + threadIdx.x;  // over B*H*D/4 float4s
  float4 a = make_float4(0.f, 0.f, 0.f, 0.f);
  const float4* p = (const float4*)partial;
#pragma unroll 8
  for (int c = 0; c < NC_; ++c) {
    float4 v = p[(size_t)c * (B_ * H_ * D_ / 4) + i];
    a.x += v.x; a.y += v.y; a.z += v.z; a.w += v.w;
  }
  ((float4*)y)[i] = a;
}

// K6: pooled[b][p] = sum_d y[b,h(p),d] * w_kv[d][P + p]
__global__ void __launch_bounds__(256) k_pooled(const float* __restrict__ y,
                                                const float* __restrict__ w_kv,
                                                float* __restrict__ pooled) {
  int idx = blockIdx.x * blockDim.x + threadIdx.x;  // B*P = 8192
  int b = idx >> 10, p = idx & 1023;
  int h = p >> 7;
  const float* yv = y + ((b * H_ + h) << 10);
  const float* wc = w_kv + P_ + p;
  float a = 0.f;
#pragma unroll 4
  for (int d = 0; d < D_; ++d) a += yv[d] * wc[(size_t)d * (2 * P_)];
  pooled[idx] = a;
}

// K7: out[b][o] = sum_p pooled[b][p] * w_out_w[o][p] + w_out_b[o]  (wave per o)
__global__ void __launch_bounds__(256) k_out(const float* __restrict__ pooled,
                                             const float* __restrict__ w_out_w,
                                             const float* __restrict__ w_out_b,
                                             float* __restrict__ out) {
  int wid = threadIdx.x >> 6, lane = threadIdx.x & 63;
  int o = blockIdx.x * 4 + wid;  // 1024 outputs
  const float4* wr = (const float4*)(w_out_w + (size_t)o * P_);
  float4 wv[4];
#pragma unroll
  for (int j = 0; j < 4; ++j) wv[j] = wr[lane + 64 * j];
  float res[B_];
#pragma unroll
  for (int b = 0; b < B_; ++b) {
    const float4* pb = (const float4*)(pooled + b * P_);
    float a = 0.f;
#pragma unroll
    for (int j = 0; j < 4; ++j) {
      float4 pv = pb[lane + 64 * j];
      a += wv[j].x * pv.x + wv[j].y * pv.y + wv[j].z * pv.z + wv[j].w * pv.w;
    }
#pragma unroll
    for (int off = 32; off; off >>= 1) a += __shfl_down(a, off, 64);
    res[b] = a;
  }
  if (lane == 0) {
    float bias = w_out_b[o];
#pragma unroll
    for (int b = 0; b < B_; ++b) out[b * OUT_ + o] = res[b] + bias;
  }
}

extern "C" void kernel_launch(void* const* d_in, const int* in_sizes, int n_in,
                              void* d_out, int out_size, void* d_ws, size_t ws_size,
                              hipStream_t stream) {
  const float* x       = (const float*)d_in[0];  // (B,T,D)
  const float* w_kv    = (const float*)d_in[1];  // (D, 2P)
  const float* query   = (const float*)d_in[2];  // (H, HD)
  const float* w_out_w = (const float*)d_in[3];  // (OUT, P)
  const float* w_out_b = (const float*)d_in[4];  // (OUT,)
  float* out = (float*)d_out;                    // (B, OUT)

  float* ws = (float*)d_ws;
  float* qp      = ws;                               // H*D          = 8192
  float* logits  = qp + H_ * D_;                     // B*H*T        = 262144
  float* weight  = logits + B_ * H_ * T_;            // B*H*T        = 262144
  float* partial = weight + B_ * H_ * T_;            // NC*B*H*D     = 4194304
  float* y       = partial + (size_t)NC_ * B_ * H_ * D_;  // B*H*D   = 65536
  float* pooled  = y + B_ * H_ * D_;                 // B*P          = 8192

  k_qproj<<<H_ * D_ / 256, 256, 0, stream>>>(w_kv, query, qp);
  k_logits<<<2048, 256, 0, stream>>>(x, qp, logits);
  k_weights<<<B_ * H_, 128, 0, stream>>>(logits, weight);
  k_yacc<<<B_ * NC_, 256, 0, stream>>>(x, weight, partial);
  k_reduce_y<<<(B_ * H_ * D_ / 4) / 256, 256, 0, stream>>>(partial, y);
  k_pooled<<<B_ * P_ / 256, 256, 0, stream>>>(y, w_kv, pooled);
  k_out<<<OUT_ / 4, 256, 0, stream>>>(pooled, w_out_w, w_out_b, out);
}

// Round 3
// 288.581 us; speedup vs baseline: 1.4074x; 1.4074x over previous
//
#include <hip/hip_runtime.h>

#define B_ 8
#define T_ 4096
#define D_ 1024
#define H_ 8
#define HD_ 128
#define P_ 1024
#define OUT_ 1024
#define W_ 128
#define NC_ 64
#define CHUNK_ 64   // T_/NC_
#define NPC_ 64     // d-chunks for pooled partials
#define PCH_ 16     // rows per pooled chunk

// K1: qp[h*D+d] = (1/sqrt(HD)) * sum_e w_kv[d][h*HD+e] * query[h][e]
// One block per row d; coalesced float4 row read; per-head 32-lane reduce.
__global__ void __launch_bounds__(256) k_qproj(const float* __restrict__ w_kv,
                                               const float* __restrict__ query,
                                               float* __restrict__ qp) {
  int d = blockIdx.x;   // 1024
  int t = threadIdx.x;  // 256, covers K-half row (1024 floats) as float4
  float4 wv = ((const float4*)(w_kv + (size_t)d * (2 * P_)))[t];
  float4 qv = ((const float4*)query)[t];  // query flat index == K-half column index
  float a = wv.x * qv.x + wv.y * qv.y + wv.z * qv.z + wv.w * qv.w;
#pragma unroll
  for (int off = 16; off; off >>= 1) a += __shfl_xor(a, off, 64);  // within 32-lane group
  if ((t & 31) == 0) {
    int h = t >> 5;  // head = (4t)>>7
    qp[h * D_ + d] = a * 0.08838834764831845f;  // 1/sqrt(128)
  }
}

// K2: logits[(b*H+h)*T + t] = dot(x[b,t,:], qp[h,:])   (wave per row-pair)
__global__ void __launch_bounds__(256) k_logits(const float* __restrict__ x,
                                                const float* __restrict__ qp,
                                                float* __restrict__ logits) {
  __shared__ float s_qp[H_ * D_];
  for (int i = threadIdx.x; i < H_ * D_ / 4; i += 256)
    ((float4*)s_qp)[i] = ((const float4*)qp)[i];
  __syncthreads();
  int wid = threadIdx.x >> 6, lane = threadIdx.x & 63;
  int nw = gridDim.x * 4;
  for (int pr = blockIdx.x * 4 + wid; pr < B_ * T_ / 2; pr += nw) {
    int row0 = pr * 2;
    const float4* xr0 = (const float4*)(x + (size_t)row0 * D_);
    const float4* xr1 = (const float4*)(x + (size_t)(row0 + 1) * D_);
    float4 xv0[4], xv1[4];
#pragma unroll
    for (int j = 0; j < 4; ++j) { xv0[j] = xr0[lane + 64 * j]; xv1[j] = xr1[lane + 64 * j]; }
    float acc0[H_], acc1[H_];
#pragma unroll
    for (int h = 0; h < H_; ++h) {
      const float4* qh = (const float4*)(s_qp + h * D_);
      float a0 = 0.f, a1 = 0.f;
#pragma unroll
      for (int j = 0; j < 4; ++j) {
        float4 q = qh[lane + 64 * j];
        a0 += xv0[j].x * q.x + xv0[j].y * q.y + xv0[j].z * q.z + xv0[j].w * q.w;
        a1 += xv1[j].x * q.x + xv1[j].y * q.y + xv1[j].z * q.z + xv1[j].w * q.w;
      }
      acc0[h] = a0; acc1[h] = a1;
    }
#pragma unroll
    for (int h = 0; h < H_; ++h) {
      float a0 = acc0[h], a1 = acc1[h];
#pragma unroll
      for (int off = 32; off; off >>= 1) {
        a0 += __shfl_down(a0, off, 64);
        a1 += __shfl_down(a1, off, 64);
      }
      if (lane == 0) {
        int b = row0 >> 12, t = row0 & (T_ - 1);
        logits[((b * H_ + h) << 12) + t] = a0;
        logits[((b * H_ + h) << 12) + t + 1] = a1;
      }
    }
  }
}

// K3: per-window softmax stats + per-token accumulated weights (incl. 1/W factor)
__global__ void __launch_bounds__(128) k_weights(const float* __restrict__ logits,
                                                 float* __restrict__ weight) {
  int bh = blockIdx.x;  // 64 = B*H
  const float* L = logits + (size_t)bh * T_;
  __shared__ float sl[T_];
  __shared__ float sm[W_], srs[W_];
  for (int i = threadIdx.x; i < T_ / 4; i += 128)
    ((float4*)sl)[i] = ((const float4*)L)[i];
  __syncthreads();
  {
    int w = threadIdx.x;  // one window per thread, 128 windows
    int start = w * 32;
    int cnt = min(64, T_ - start);  // window 127 has only 32 valid entries
    float m = -1e30f;
    for (int i = 0; i < cnt; ++i) m = fmaxf(m, sl[start + i]);
    float s = 0.f;
    for (int i = 0; i < cnt; ++i) s += __expf(sl[start + i] - m);
    sm[w] = m;
    srs[w] = 1.0f / s;
  }
  __syncthreads();
  const float invW = 1.0f / (float)W_;
  for (int t = threadIdx.x; t < T_; t += 128) {
    float l = sl[t];
    int w1 = t >> 5;  // every token is in windows w1 and w1-1 (when w1>0)
    float acc = __expf(l - sm[w1]) * srs[w1];
    if (w1 > 0) acc += __expf(l - sm[w1 - 1]) * srs[w1 - 1];
    weight[(size_t)bh * T_ + t] = acc * invW;
  }
}

// K4: partial[c][b][h][d] = sum_{t in chunk c} weight[b,h,t] * x[b,t,d]
__global__ void __launch_bounds__(256) k_yacc(const float* __restrict__ x,
                                              const float* __restrict__ weight,
                                              float* __restrict__ partial) {
  int b = blockIdx.x >> 6;  // NC_=64
  int c = blockIdx.x & 63;
  int t0 = c * CHUNK_;
  __shared__ float sw[H_][CHUNK_];
  for (int i = threadIdx.x; i < H_ * CHUNK_; i += 256) {
    int h = i / CHUNK_, tt = i % CHUNK_;
    sw[h][tt] = weight[((b * H_ + h) << 12) + t0 + tt];
  }
  __syncthreads();
  float4 acc[H_];
#pragma unroll
  for (int h = 0; h < H_; ++h) acc[h] = make_float4(0.f, 0.f, 0.f, 0.f);
  const float4* xb = (const float4*)(x + ((size_t)b * T_ + t0) * D_);
  for (int tt = 0; tt < CHUNK_; ++tt) {
    float4 xv = xb[tt * (D_ / 4) + threadIdx.x];
#pragma unroll
    for (int h = 0; h < H_; ++h) {
      float wv = sw[h][tt];
      acc[h].x += wv * xv.x; acc[h].y += wv * xv.y;
      acc[h].z += wv * xv.z; acc[h].w += wv * xv.w;
    }
  }
  float4* pp = (float4*)(partial + (((size_t)(c * B_ + b) * H_) << 10));
#pragma unroll
  for (int h = 0; h < H_; ++h) pp[h * (D_ / 4) + threadIdx.x] = acc[h];
}

// K5: y[b*H+h][d] = sum_c partial[c][b][h][d]
__global__ void __launch_bounds__(256) k_reduce_y(const float* __restrict__ partial,
                                                  float* __restrict__ y) {
  int i = blockIdx.x * blockDim.x + threadIdx.x;  // over B*H*D/4 float4s
  float4 a = make_float4(0.f, 0.f, 0.f, 0.f);
  const float4* p = (const float4*)partial;
#pragma unroll 8
  for (int c = 0; c < NC_; ++c) {
    float4 v = p[(size_t)c * (B_ * H_ * D_ / 4) + i];
    a.x += v.x; a.y += v.y; a.z += v.z; a.w += v.w;
  }
  ((float4*)y)[i] = a;
}

// K6a: ppart[c][b][p] = sum_{d in chunk c} y[b,h(p),d] * w_kv[d][P+p]
// Coalesced row reads of w_kv; y broadcast from LDS.
__global__ void __launch_bounds__(256) k_pooled_part(const float* __restrict__ y,
                                                     const float* __restrict__ w_kv,
                                                     float* __restrict__ ppart) {
  int c = blockIdx.x;   // NPC_=64 chunks of PCH_=16 rows
  int d0 = c * PCH_;
  int t = threadIdx.x;  // owns columns 4t..4t+3 of P
  int h = t >> 5;       // head of those columns
  __shared__ float sy[PCH_][B_ * H_];  // sy[dd][b*8+h]
  for (int i = t; i < PCH_ * B_ * H_; i += 256) {
    int dd = i >> 6, bh = i & 63;
    sy[dd][bh] = y[((size_t)bh << 10) + d0 + dd];
  }
  __syncthreads();
  float4 acc[B_];
#pragma unroll
  for (int b = 0; b < B_; ++b) acc[b] = make_float4(0.f, 0.f, 0.f, 0.f);
#pragma unroll
  for (int dd = 0; dd < PCH_; ++dd) {
    float4 wv = ((const float4*)(w_kv + (size_t)(d0 + dd) * (2 * P_) + P_))[t];
#pragma unroll
    for (int b = 0; b < B_; ++b) {
      float yv = sy[dd][b * H_ + h];
      acc[b].x += yv * wv.x; acc[b].y += yv * wv.y;
      acc[b].z += yv * wv.z; acc[b].w += yv * wv.w;
    }
  }
#pragma unroll
  for (int b = 0; b < B_; ++b)
    ((float4*)(ppart + (((size_t)c * B_ + b) << 10)))[t] = acc[b];
}

// K6b: pooled[b][p] = sum_c ppart[c][b][p]
__global__ void __launch_bounds__(256) k_reduce_pooled(const float* __restrict__ ppart,
                                                       float* __restrict__ pooled) {
  int i = blockIdx.x * 256 + threadIdx.x;  // 2048 float4s over (b,p)
  int b = i >> 8, p4 = i & 255;
  float4 a = make_float4(0.f, 0.f, 0.f, 0.f);
  const float4* p = (const float4*)ppart;
#pragma unroll 8
  for (int c = 0; c < NPC_; ++c) {
    float4 v = p[((c * B_ + b) << 8) + p4];
    a.x += v.x; a.y += v.y; a.z += v.z; a.w += v.w;
  }
  ((float4*)pooled)[i] = a;
}

// K7: out[b][o] = sum_p pooled[b][p] * w_out_w[o][p] + w_out_b[o]  (wave per o)
__global__ void __launch_bounds__(256) k_out(const float* __restrict__ pooled,
                                             const float* __restrict__ w_out_w,
                                             const float* __restrict__ w_out_b,
                                             float* __restrict__ out) {
  int wid = threadIdx.x >> 6, lane = threadIdx.x & 63;
  int o = blockIdx.x * 4 + wid;  // 1024 outputs
  const float4* wr = (const float4*)(w_out_w + (size_t)o * P_);
  float4 wv[4];
#pragma unroll
  for (int j = 0; j < 4; ++j) wv[j] = wr[lane + 64 * j];
  float res[B_];
#pragma unroll
  for (int b = 0; b < B_; ++b) {
    const float4* pb = (const float4*)(pooled + b * P_);
    float a = 0.f;
#pragma unroll
    for (int j = 0; j < 4; ++j) {
      float4 pv = pb[lane + 64 * j];
      a += wv[j].x * pv.x + wv[j].y * pv.y + wv[j].z * pv.z + wv[j].w * pv.w;
    }
#pragma unroll
    for (int off = 32; off; off >>= 1) a += __shfl_down(a, off, 64);
    res[b] = a;
  }
  if (lane == 0) {
    float bias = w_out_b[o];
#pragma unroll
    for (int b = 0; b < B_; ++b) out[b * OUT_ + o] = res[b] + bias;
  }
}

extern "C" void kernel_launch(void* const* d_in, const int* in_sizes, int n_in,
                              void* d_out, int out_size, void* d_ws, size_t ws_size,
                              hipStream_t stream) {
  const float* x       = (const float*)d_in[0];  // (B,T,D)
  const float* w_kv    = (const float*)d_in[1];  // (D, 2P)
  const float* query   = (const float*)d_in[2];  // (H, HD)
  const float* w_out_w = (const float*)d_in[3];  // (OUT, P)
  const float* w_out_b = (const float*)d_in[4];  // (OUT,)
  float* out = (float*)d_out;                    // (B, OUT)

  float* ws = (float*)d_ws;
  float* qp      = ws;                               // H*D          = 8192
  float* logits  = qp + H_ * D_;                     // B*H*T        = 262144
  float* weight  = logits + B_ * H_ * T_;            // B*H*T        = 262144
  float* partial = weight + B_ * H_ * T_;            // NC*B*H*D     = 4194304
  float* y       = partial + (size_t)NC_ * B_ * H_ * D_;  // B*H*D   = 65536
  float* pooled  = y + B_ * H_ * D_;                 // B*P          = 8192
  // ppart reuses the yacc partial buffer (free after k_reduce_y): NPC*B*P = 524288 floats
  float* ppart   = partial;

  k_qproj<<<D_, 256, 0, stream>>>(w_kv, query, qp);
  k_logits<<<2048, 256, 0, stream>>>(x, qp, logits);
  k_weights<<<B_ * H_, 128, 0, stream>>>(logits, weight);
  k_yacc<<<B_ * NC_, 256, 0, stream>>>(x, weight, partial);
  k_reduce_y<<<(B_ * H_ * D_ / 4) / 256, 256, 0, stream>>>(partial, y);
  k_pooled_part<<<NPC_, 256, 0, stream>>>(y, w_kv, ppart);
  k_reduce_pooled<<<(B_ * P_ / 4) / 256, 256, 0, stream>>>(ppart, pooled);
  k_out<<<OUT_ / 4, 256, 0, stream>>>(pooled, w_out_w, w_out_b, out);
}